// Round 3
// baseline (905.998 us; speedup 1.0000x reference)
//
#include <hip/hip_runtime.h>
#include <cstdint>

using u8 = unsigned char;
using u64 = unsigned long long;

typedef _Float16 f16x8 __attribute__((ext_vector_type(8)));
typedef float f32x4 __attribute__((ext_vector_type(4)));

__device__ __forceinline__ unsigned sortable_f32(float f) {
  unsigned u = __float_as_uint(f);
  return (u & 0x80000000u) ? ~u : (u | 0x80000000u);
}

__device__ __forceinline__ void gload16(const void* g, void* l) {
  __builtin_amdgcn_global_load_lds((const __attribute__((address_space(1))) void*)g,
                                   (__attribute__((address_space(3))) void*)l, 16, 0, 0);
}

// ---- convert fp32 [B][C][N] -> packed fp16 split [B][N][C/32][hi 64B | lo 64B]
__global__ __launch_bounds__(256) void split_convert(const float* __restrict__ in,
                                                     u8* __restrict__ out,
                                                     int C, int N) {
  const int n = blockIdx.y * 256 + threadIdx.x;
  const int c0 = blockIdx.x * 32;
  const int b = blockIdx.z;
  const float* inB = in + (size_t)b * C * N;
  f16x8 hv[4], lv[4];
#pragma unroll
  for (int g = 0; g < 4; ++g)
#pragma unroll
    for (int e = 0; e < 8; ++e) {
      float x = inB[(size_t)(c0 + g * 8 + e) * N + n];
      _Float16 h = (_Float16)x;
      float r = (x - (float)h) * 4096.f;  // exact split; scale dodges fp16 subnormals
      hv[g][e] = h;
      lv[g][e] = (_Float16)r;
    }
  const int Kc = C >> 5;
  u8* o = out + ((size_t)((size_t)b * N + n) * Kc + (c0 >> 5)) * 128;
#pragma unroll
  for (int g = 0; g < 4; ++g) {
    *(f16x8*)(o + g * 16) = hv[g];
    *(f16x8*)(o + 64 + g * 16) = lv[g];
  }
}

// ---- half-norms: hn[b][n] = 0.5 * sum_c t^2 ---------------------------------
__global__ __launch_bounds__(256) void hn_kernel(const float* __restrict__ tar,
                                                 float* __restrict__ hn,
                                                 int C, int N) {
  __shared__ float ps[256];
  int b = blockIdx.y;
  int nb = blockIdx.x * 32;
  int tn = threadIdx.x & 31, tg = threadIdx.x >> 5;
  const float* t = tar + (size_t)b * C * N + nb + tn;
  int cpg = C >> 3;
  int c0 = tg * cpg;
  float s = 0.f;
  for (int c = c0; c < c0 + cpg; ++c) {
    float v = t[(size_t)c * N];
    s = fmaf(v, v, s);
  }
  ps[threadIdx.x] = s;
  __syncthreads();
  if (threadIdx.x < 32) {
    float acc = 0.f;
#pragma unroll
    for (int g = 0; g < 8; ++g) acc += ps[g * 32 + threadIdx.x];
    hn[(size_t)b * N + nb + threadIdx.x] = 0.5f * acc;
  }
}

// ---- MFMA fp16-split GEMM + fused argmin, 2-deep counted-vmcnt pipeline -----
// score(m,n) = hn[n] - dot(s_m, t_n); dot = hh + ll/4096 via 3 MFMA passes.
template <int MI, int NJ>
__global__ __launch_bounds__(256, 2) void nn_mfma(
    const u8* __restrict__ Ac, const u8* __restrict__ Bc,
    const float* __restrict__ hn, u64* __restrict__ bestkey,
    int M, int N, int Kc, int mBlocks, int nBlocks) {
  constexpr int BM = 32 * MI, BN = 32 * NJ;
  constexpr int ABYTES = BM * 128;
  constexpr int BUFSZ = (BM + BN) * 128;
  __shared__ u8 smem[2 * BUFSZ];

  const int tid = threadIdx.x;
  const int lane = tid & 63;
  const int wid = tid >> 6;
  const int wrow = wid >> 1, wcol = wid & 1;
  const int lr = lane & 15, kh = lane >> 4;

  // XCD-bijective swizzle (nwg % 8 == 0), n-fastest decode within a chunk so
  // consecutive same-XCD blocks share the A panel in that XCD's L2.
  const int cpx = (int)gridDim.x >> 3;
  const int bid = (int)blockIdx.x;
  const int sbid = (bid & 7) * cpx + (bid >> 3);
  const int perB = mBlocks * nBlocks;
  const int b = sbid / perB;
  const int rr = sbid - b * perB;
  const int mbase = (rr / nBlocks) * BM;
  const int nbase = (rr % nBlocks) * BN;
  const size_t rstride = (size_t)Kc * 128;

  // staging: source pre-swizzled chunk^=(row&7); LDS dest linear
  const int trow = tid >> 3, tp = tid & 7;
  const int tswz = (tp ^ (trow & 7)) << 4;
  const u8* aBase = Ac + ((size_t)b * M + mbase + trow) * rstride + tswz;
  const u8* bBase = Bc + ((size_t)b * N + nbase + trow) * rstride + tswz;

  const int swz = (lr & 7) << 4;
  const int aoff = (wrow * MI * 16 + lr) * 128;
  const int boff = ABYTES + (wcol * NJ * 16 + lr) * 128;
  const int hi_s = (kh << 4) ^ swz;
  const int lo_s = ((kh + 4) << 4) ^ swz;

  f32x4 hh[MI][NJ], ll[MI][NJ];
#pragma unroll
  for (int i = 0; i < MI; ++i)
#pragma unroll
    for (int j = 0; j < NJ; ++j) {
      hh[i][j] = f32x4{0.f, 0.f, 0.f, 0.f};
      ll[i][j] = f32x4{0.f, 0.f, 0.f, 0.f};
    }

  auto STAGE = [&](int kt, int p) {
    const u8* aS = aBase + (size_t)kt * 128;
    const u8* bS = bBase + (size_t)kt * 128;
    u8* dst = smem + p * BUFSZ + tid * 16;
#pragma unroll
    for (int v = 0; v < MI; ++v)
      gload16(aS + (size_t)v * 32 * rstride, dst + v * 4096);
#pragma unroll
    for (int w = 0; w < NJ; ++w)
      gload16(bS + (size_t)w * 32 * rstride, dst + ABYTES + w * 4096);
  };

  auto COMPUTE = [&](int p) {
    const u8* base = smem + p * BUFSZ;
    f16x8 ah[MI], al[MI], bh[NJ], bl[NJ];
#pragma unroll
    for (int i = 0; i < MI; ++i) {
      ah[i] = *(const f16x8*)(base + aoff + i * 2048 + hi_s);
      al[i] = *(const f16x8*)(base + aoff + i * 2048 + lo_s);
    }
#pragma unroll
    for (int j = 0; j < NJ; ++j) {
      bh[j] = *(const f16x8*)(base + boff + j * 2048 + hi_s);
      bl[j] = *(const f16x8*)(base + boff + j * 2048 + lo_s);
    }
#pragma unroll
    for (int i = 0; i < MI; ++i)
#pragma unroll
      for (int j = 0; j < NJ; ++j) {
        hh[i][j] = __builtin_amdgcn_mfma_f32_16x16x32_f16(ah[i], bh[j], hh[i][j], 0, 0, 0);
        ll[i][j] = __builtin_amdgcn_mfma_f32_16x16x32_f16(ah[i], bl[j], ll[i][j], 0, 0, 0);
        ll[i][j] = __builtin_amdgcn_mfma_f32_16x16x32_f16(al[i], bh[j], ll[i][j], 0, 0, 0);
      }
  };

  STAGE(0, 0);
  for (int kt = 0; kt < Kc - 1; ++kt) {
    const int p = kt & 1;
    asm volatile("" ::: "memory");
    STAGE(kt + 1, p ^ 1);
    // wait for buf p only (one stage-group = MI+NJ loads stays in flight)
    if constexpr (MI + NJ == 8) {
      asm volatile("s_waitcnt vmcnt(8)" ::: "memory");
    } else {
      asm volatile("s_waitcnt vmcnt(6)" ::: "memory");
    }
    __builtin_amdgcn_s_barrier();
    COMPUTE(p);
    asm volatile("" ::: "memory");
    __builtin_amdgcn_s_barrier();
  }
  asm volatile("s_waitcnt vmcnt(0)" ::: "memory");
  __builtin_amdgcn_s_barrier();
  COMPUTE((Kc - 1) & 1);

  // fused argmin: C/D layout col=lane&15, row=(lane>>4)*4+reg
  const float inv4096 = 2.44140625e-4f;
  const float* hnB = hn + (size_t)b * N;
  float hnv[NJ];
  int ncol[NJ];
#pragma unroll
  for (int j = 0; j < NJ; ++j) {
    ncol[j] = nbase + wcol * NJ * 16 + j * 16 + lr;
    hnv[j] = hnB[ncol[j]];
  }
#pragma unroll
  for (int i = 0; i < MI; ++i)
#pragma unroll
    for (int r = 0; r < 4; ++r) {
      u64 k = ~0ull;
#pragma unroll
      for (int j = 0; j < NJ; ++j) {
        float dot = hh[i][j][r] + ll[i][j][r] * inv4096;
        float val = hnv[j] - dot;
        u64 key = ((u64)sortable_f32(val) << 32) | (unsigned)ncol[j];
        if (key < k) k = key;
      }
#pragma unroll
      for (int off = 8; off >= 1; off >>= 1) {
        unsigned lo32 = (unsigned)k, hi32 = (unsigned)(k >> 32);
        unsigned olo = __shfl_xor(lo32, off);
        unsigned ohi = __shfl_xor(hi32, off);
        u64 o = ((u64)ohi << 32) | olo;
        if (o < k) k = o;
      }
      if (lr == 0)
        atomicMin(&bestkey[(size_t)b * M + mbase + wrow * MI * 16 + i * 16 + kh * 4 + r], k);
    }
}

// ---------------- epilogue kernels -------------------------------------------
__global__ __launch_bounds__(256) void copy_src1(const float4* __restrict__ s,
                                                 float4* __restrict__ o) {
  size_t i = (size_t)blockIdx.x * 256 + threadIdx.x;
  size_t b = i >> 20;
  size_t r = i & ((1u << 20) - 1);
  o[b * (size_t)(6144 * 1024) + r] = s[i];
}

__global__ __launch_bounds__(256) void gather_nn1(const float* __restrict__ tar,
                                                  const u64* __restrict__ bk,
                                                  float* __restrict__ out) {
  int b = blockIdx.y, c = blockIdx.x;
  const float* trow = tar + ((size_t)b * 1024 + c) * 4096;
  const u64* bkb = bk + (size_t)b * 4096;
  float* orow = out + ((size_t)b * 6144 + 1024 + c) * 4096;
  for (int p = threadIdx.x; p < 4096; p += 256) {
    int idx = (int)(unsigned)bkb[p];
    orow[p] = trow[idx];
  }
}

__global__ __launch_bounds__(256) void upsample2(const float* __restrict__ src2,
                                                 const float* __restrict__ tar2,
                                                 const u64* __restrict__ bk2,
                                                 float* __restrict__ out) {
  __shared__ float row[1024];
  int b = blockIdx.y, c = blockIdx.x;
  if (c < 2048) {
    const float* in = src2 + ((size_t)b * 2048 + c) * 1024;
    for (int p = threadIdx.x; p < 1024; p += 256) row[p] = in[p];
  } else {
    const float* trow = tar2 + ((size_t)b * 2048 + (c - 2048)) * 1024;
    const u64* bkb = bk2 + (size_t)b * 1024;
    for (int p = threadIdx.x; p < 1024; p += 256) {
      int idx = (int)(unsigned)bkb[p];
      row[p] = trow[idx];
    }
  }
  __syncthreads();
  float* orow = out + ((size_t)b * 6144 + 2048 + c) * 4096;
  for (int q = threadIdx.x; q < 4096; q += 256) {
    int y = q >> 6, x = q & 63;
    int ky = y >> 1, kx = x >> 1;
    int y0, y1, x0, x1;
    float wy0, wy1, wx0, wx1;
    if (y & 1) { y0 = ky; y1 = (ky + 1 < 32) ? ky + 1 : 31; wy0 = 0.75f; wy1 = 0.25f; }
    else       { y0 = (ky > 0) ? ky - 1 : 0; y1 = ky;       wy0 = 0.25f; wy1 = 0.75f; }
    if (x & 1) { x0 = kx; x1 = (kx + 1 < 32) ? kx + 1 : 31; wx0 = 0.75f; wx1 = 0.25f; }
    else       { x0 = (kx > 0) ? kx - 1 : 0; x1 = kx;       wx0 = 0.25f; wx1 = 0.75f; }
    float v = wy0 * (wx0 * row[y0 * 32 + x0] + wx1 * row[y0 * 32 + x1]) +
              wy1 * (wx0 * row[y1 * 32 + x0] + wx1 * row[y1 * 32 + x1]);
    orow[q] = v;
  }
}

// ---------------- launch -----------------------------------------------------
extern "C" void kernel_launch(void* const* d_in, const int* in_sizes, int n_in,
                              void* d_out, int out_size, void* d_ws, size_t ws_size,
                              hipStream_t stream) {
  const float* src1 = (const float*)d_in[0];  // [4,1024,64,64]
  const float* tar1 = (const float*)d_in[1];
  const float* src2 = (const float*)d_in[2];  // [4,2048,32,32]
  const float* tar2 = (const float*)d_in[3];
  float* out = (float*)d_out;                 // [4,6144,64,64] = 384 MiB

  // converted fp16-split tensors live in d_out's space as scratch (192 MiB),
  // fully overwritten by the epilogue afterwards.
  u8* scratch = (u8*)d_out;
  u8* c_src1 = scratch;                         // 64 MiB  [4,4096,32,128B]
  u8* c_tar1 = scratch + (64ull << 20);         // 64 MiB
  u8* c_src2 = scratch + (128ull << 20);        // 32 MiB  [4,1024,64,128B]
  u8* c_tar2 = scratch + (160ull << 20);        // 32 MiB

  float* hn1 = (float*)d_ws;          // 4*4096 f32
  float* hn2 = hn1 + 4 * 4096;        // 4*1024 f32
  u64* bk1 = (u64*)(hn2 + 4 * 1024);  // 4*4096 u64
  u64* bk2 = bk1 + 4 * 4096;          // 4*1024 u64

  split_convert<<<dim3(32, 16, 4), 256, 0, stream>>>(src1, c_src1, 1024, 4096);
  split_convert<<<dim3(32, 16, 4), 256, 0, stream>>>(tar1, c_tar1, 1024, 4096);
  split_convert<<<dim3(64, 4, 4), 256, 0, stream>>>(src2, c_src2, 2048, 1024);
  split_convert<<<dim3(64, 4, 4), 256, 0, stream>>>(tar2, c_tar2, 2048, 1024);

  hn_kernel<<<dim3(128, 4), 256, 0, stream>>>(tar1, hn1, 1024, 4096);
  hn_kernel<<<dim3(32, 4), 256, 0, stream>>>(tar2, hn2, 2048, 1024);
  hipMemsetAsync(bk1, 0xFF, (size_t)(4 * 4096 + 4 * 1024) * sizeof(u64), stream);

  // level 1: M=N=4096, K=1024 (Kc=32), tile 128x128; 32x32 m/n blocks
  nn_mfma<4, 4><<<4096, 256, 0, stream>>>(c_src1, c_tar1, hn1, bk1, 4096, 4096, 32, 32, 32);
  // level 2: M=N=1024, K=2048 (Kc=64), tile 128x64; 8x16 m/n blocks
  nn_mfma<4, 2><<<512, 256, 0, stream>>>(c_src2, c_tar2, hn2, bk2, 1024, 1024, 64, 8, 16);

  copy_src1<<<16384, 256, 0, stream>>>((const float4*)src1, (float4*)out);
  gather_nn1<<<dim3(1024, 4), 256, 0, stream>>>(tar1, bk1, out);
  upsample2<<<dim3(4096, 4), 256, 0, stream>>>(src2, tar2, bk2, out);
}

// Round 4
// 880.179 us; speedup vs baseline: 1.0293x; 1.0293x over previous
//
#include <hip/hip_runtime.h>
#include <cstdint>

using u8 = unsigned char;
using u64 = unsigned long long;

typedef _Float16 f16x8 __attribute__((ext_vector_type(8)));
typedef float f32x4 __attribute__((ext_vector_type(4)));

__device__ __forceinline__ unsigned sortable_f32(float f) {
  unsigned u = __float_as_uint(f);
  return (u & 0x80000000u) ? ~u : (u | 0x80000000u);
}

__device__ __forceinline__ void gload16(const void* g, void* l) {
  __builtin_amdgcn_global_load_lds((const __attribute__((address_space(1))) void*)g,
                                   (__attribute__((address_space(3))) void*)l, 16, 0, 0);
}

// ---- convert fp32 [B][C][N] -> packed fp16 split [B][N][C/32][hi 64B | lo 64B]
__global__ __launch_bounds__(256) void split_convert(const float* __restrict__ in,
                                                     u8* __restrict__ out,
                                                     int C, int N) {
  const int n = blockIdx.y * 256 + threadIdx.x;
  const int c0 = blockIdx.x * 32;
  const int b = blockIdx.z;
  const float* inB = in + (size_t)b * C * N;
  f16x8 hv[4], lv[4];
#pragma unroll
  for (int g = 0; g < 4; ++g)
#pragma unroll
    for (int e = 0; e < 8; ++e) {
      float x = inB[(size_t)(c0 + g * 8 + e) * N + n];
      _Float16 h = (_Float16)x;
      float r = (x - (float)h) * 4096.f;  // exact split; scale dodges fp16 subnormals
      hv[g][e] = h;
      lv[g][e] = (_Float16)r;
    }
  const int Kc = C >> 5;
  u8* o = out + ((size_t)((size_t)b * N + n) * Kc + (c0 >> 5)) * 128;
#pragma unroll
  for (int g = 0; g < 4; ++g) {
    *(f16x8*)(o + g * 16) = hv[g];
    *(f16x8*)(o + 64 + g * 16) = lv[g];
  }
}

// ---- half-norms: hn[b][n] = 0.5 * sum_c t^2 ---------------------------------
__global__ __launch_bounds__(256) void hn_kernel(const float* __restrict__ tar,
                                                 float* __restrict__ hn,
                                                 int C, int N) {
  __shared__ float ps[256];
  int b = blockIdx.y;
  int nb = blockIdx.x * 32;
  int tn = threadIdx.x & 31, tg = threadIdx.x >> 5;
  const float* t = tar + (size_t)b * C * N + nb + tn;
  int cpg = C >> 3;
  int c0 = tg * cpg;
  float s = 0.f;
  for (int c = c0; c < c0 + cpg; ++c) {
    float v = t[(size_t)c * N];
    s = fmaf(v, v, s);
  }
  ps[threadIdx.x] = s;
  __syncthreads();
  if (threadIdx.x < 32) {
    float acc = 0.f;
#pragma unroll
    for (int g = 0; g < 8; ++g) acc += ps[g * 32 + threadIdx.x];
    hn[(size_t)b * N + nb + threadIdx.x] = 0.5f * acc;
  }
}

// ---- 8-wave 8-phase MFMA fp16-split GEMM + fused argmin ---------------------
// Tile BM x 128, 512 threads (2 wave-rows x 4 wave-cols), 3 LDS buffers,
// 2-deep prefetch, counted vmcnt, per-phase barrier + setprio.
// score(m,n) = hn[n] - dot; dot = hh + ll/4096 via 3 MFMA passes.
template <int MREP>
__global__ __launch_bounds__(512, 2) void nn_mfma8(
    const u8* __restrict__ Ac, const u8* __restrict__ Bc,
    const float* __restrict__ hn, u64* __restrict__ bestkey,
    int M, int N, int Kc, int mBlocks, int nBlocks) {
  constexpr int BM = 32 * MREP;        // 256 (MREP=8) or 128 (MREP=4)
  constexpr int BN = 128;
  constexpr int ABYTES = BM * 128;
  constexpr int BUFSZ = (BM + BN) * 128;
  constexpr int GL_A = MREP / 2;       // A gloads per thread per stage
  constexpr int GL = GL_A + 2;         // total gloads per thread per stage
  __shared__ u8 smem[3 * BUFSZ];

  const int tid = threadIdx.x;
  const int lane = tid & 63;
  const int wid = tid >> 6;            // 0..7
  const int wrow = wid >> 2;           // 0..1
  const int wcol = wid & 3;            // 0..3
  const int lr = lane & 15, kh = lane >> 4;

  // XCD-bijective swizzle; within an XCD chunk: n-group-of-4 inner, m mid,
  // n outer -> concurrent window ~8m x 4n shares both panels in that L2.
  const int cpx = (int)gridDim.x >> 3;
  const int bid = (int)blockIdx.x;
  const int sbid = (bid & 7) * cpx + (bid >> 3);
  const int perB = mBlocks * nBlocks;
  const int b = sbid / perB;
  const int rr = sbid - b * perB;
  const int n1 = rr & 3;
  const int t2 = rr >> 2;
  const int mb = t2 & (mBlocks - 1);
  const int n2 = t2 / mBlocks;
  const int mbase = mb * BM;
  const int nbase = (n2 * 4 + n1) * BN;
  const size_t rstride = (size_t)Kc * 128;

  // staging: source pre-swizzled chunk^=(row&7); LDS dest linear
  const int trow = tid >> 3, tp = tid & 7;
  const int tswz = (tp ^ (trow & 7)) << 4;
  const u8* aBase = Ac + ((size_t)b * M + mbase + trow) * rstride + tswz;
  const u8* bBase = Bc + ((size_t)b * N + nbase + trow) * rstride + tswz;

  const int swz = (lr & 7) << 4;
  const int hi_s = (kh << 4) ^ swz;
  const int lo_s = ((kh + 4) << 4) ^ swz;
  const int arow0 = (wrow * (BM / 2) + lr) * 128;
  const int brow0 = ABYTES + (wcol * 32 + lr) * 128;

  f32x4 hh[MREP][2], ll[MREP][2];
#pragma unroll
  for (int i = 0; i < MREP; ++i)
#pragma unroll
    for (int j = 0; j < 2; ++j) {
      hh[i][j] = f32x4{0.f, 0.f, 0.f, 0.f};
      ll[i][j] = f32x4{0.f, 0.f, 0.f, 0.f};
    }

  auto STAGE = [&](int kt, int p) {
    const u8* aS = aBase + (size_t)kt * 128;
    const u8* bS = bBase + (size_t)kt * 128;
    u8* dst = smem + p * BUFSZ + tid * 16;
#pragma unroll
    for (int v = 0; v < GL_A; ++v)
      gload16(aS + (size_t)v * 64 * rstride, dst + v * 8192);
#pragma unroll
    for (int w = 0; w < 2; ++w)
      gload16(bS + (size_t)w * 64 * rstride, dst + ABYTES + w * 8192);
  };

  STAGE(0, 0);
  STAGE(1, 1);
  int pcur = 0;
  for (int kt = 0; kt < Kc; ++kt) {
    int pn = pcur + 2; if (pn >= 3) pn -= 3;
    if (kt + 2 < Kc) STAGE(kt + 2, pn);
    // counted vmcnt: keep the 2 prefetched stages in flight, never drain
    if (kt + 2 < Kc) {
      if constexpr (GL == 6) asm volatile("s_waitcnt vmcnt(12)" ::: "memory");
      else                   asm volatile("s_waitcnt vmcnt(8)" ::: "memory");
    } else if (kt + 1 < Kc) {
      if constexpr (GL == 6) asm volatile("s_waitcnt vmcnt(6)" ::: "memory");
      else                   asm volatile("s_waitcnt vmcnt(4)" ::: "memory");
    } else {
      asm volatile("s_waitcnt vmcnt(0)" ::: "memory");
    }
    __builtin_amdgcn_s_barrier();

    const u8* base = smem + pcur * BUFSZ;
    f16x8 bh[2], bl[2];
#pragma unroll
    for (int j = 0; j < 2; ++j) {
      bh[j] = *(const f16x8*)(base + brow0 + j * 2048 + hi_s);
      bl[j] = *(const f16x8*)(base + brow0 + j * 2048 + lo_s);
    }
#pragma unroll
    for (int ph = 0; ph < MREP / 2; ++ph) {
      f16x8 ah[2], al[2];
#pragma unroll
      for (int i2 = 0; i2 < 2; ++i2) {
        const int ao = arow0 + (2 * ph + i2) * 2048;
        ah[i2] = *(const f16x8*)(base + ao + hi_s);
        al[i2] = *(const f16x8*)(base + ao + lo_s);
      }
      asm volatile("" ::: "memory");
      __builtin_amdgcn_s_barrier();
      __builtin_amdgcn_s_setprio(1);
#pragma unroll
      for (int i2 = 0; i2 < 2; ++i2)
#pragma unroll
        for (int j = 0; j < 2; ++j) {
          const int i = 2 * ph + i2;
          hh[i][j] = __builtin_amdgcn_mfma_f32_16x16x32_f16(ah[i2], bh[j], hh[i][j], 0, 0, 0);
          ll[i][j] = __builtin_amdgcn_mfma_f32_16x16x32_f16(ah[i2], bl[j], ll[i][j], 0, 0, 0);
          ll[i][j] = __builtin_amdgcn_mfma_f32_16x16x32_f16(al[i2], bh[j], ll[i][j], 0, 0, 0);
        }
      __builtin_amdgcn_s_setprio(0);
      asm volatile("" ::: "memory");
      __builtin_amdgcn_s_barrier();
    }
    pcur = (pcur + 1 == 3) ? 0 : pcur + 1;
  }

  // fused argmin: C/D layout col=lane&15, row=(lane>>4)*4+reg
  const float inv4096 = 2.44140625e-4f;
  const float* hnB = hn + (size_t)b * N;
  float hnv[2];
  int ncol[2];
#pragma unroll
  for (int j = 0; j < 2; ++j) {
    ncol[j] = nbase + wcol * 32 + j * 16 + lr;
    hnv[j] = hnB[ncol[j]];
  }
#pragma unroll
  for (int i = 0; i < MREP; ++i)
#pragma unroll
    for (int r = 0; r < 4; ++r) {
      u64 k = ~0ull;
#pragma unroll
      for (int j = 0; j < 2; ++j) {
        float dot = hh[i][j][r] + ll[i][j][r] * inv4096;
        float val = hnv[j] - dot;
        u64 key = ((u64)sortable_f32(val) << 32) | (unsigned)ncol[j];
        if (key < k) k = key;
      }
#pragma unroll
      for (int off = 8; off >= 1; off >>= 1) {
        unsigned lo32 = (unsigned)k, hi32 = (unsigned)(k >> 32);
        unsigned olo = __shfl_xor(lo32, off);
        unsigned ohi = __shfl_xor(hi32, off);
        u64 o = ((u64)ohi << 32) | olo;
        if (o < k) k = o;
      }
      if (lr == 0)
        atomicMin(&bestkey[(size_t)b * M + mbase + wrow * (BM / 2) + i * 16 + kh * 4 + r], k);
    }
}

// ---------------- epilogue kernels -------------------------------------------
__global__ __launch_bounds__(256) void copy_src1(const float4* __restrict__ s,
                                                 float4* __restrict__ o) {
  size_t i = (size_t)blockIdx.x * 256 + threadIdx.x;
  size_t b = i >> 20;
  size_t r = i & ((1u << 20) - 1);
  o[b * (size_t)(6144 * 1024) + r] = s[i];
}

__global__ __launch_bounds__(256) void gather_nn1(const float* __restrict__ tar,
                                                  const u64* __restrict__ bk,
                                                  float* __restrict__ out) {
  int b = blockIdx.y, c = blockIdx.x;
  const float* trow = tar + ((size_t)b * 1024 + c) * 4096;
  const u64* bkb = bk + (size_t)b * 4096;
  float* orow = out + ((size_t)b * 6144 + 1024 + c) * 4096;
  for (int p = threadIdx.x; p < 4096; p += 256) {
    int idx = (int)(unsigned)bkb[p];
    orow[p] = trow[idx];
  }
}

__global__ __launch_bounds__(256) void upsample2(const float* __restrict__ src2,
                                                 const float* __restrict__ tar2,
                                                 const u64* __restrict__ bk2,
                                                 float* __restrict__ out) {
  __shared__ float row[1024];
  int b = blockIdx.y, c = blockIdx.x;
  if (c < 2048) {
    const float* in = src2 + ((size_t)b * 2048 + c) * 1024;
    for (int p = threadIdx.x; p < 1024; p += 256) row[p] = in[p];
  } else {
    const float* trow = tar2 + ((size_t)b * 2048 + (c - 2048)) * 1024;
    const u64* bkb = bk2 + (size_t)b * 1024;
    for (int p = threadIdx.x; p < 1024; p += 256) {
      int idx = (int)(unsigned)bkb[p];
      row[p] = trow[idx];
    }
  }
  __syncthreads();
  float* orow = out + ((size_t)b * 6144 + 2048 + c) * 4096;
  for (int q = threadIdx.x; q < 4096; q += 256) {
    int y = q >> 6, x = q & 63;
    int ky = y >> 1, kx = x >> 1;
    int y0, y1, x0, x1;
    float wy0, wy1, wx0, wx1;
    if (y & 1) { y0 = ky; y1 = (ky + 1 < 32) ? ky + 1 : 31; wy0 = 0.75f; wy1 = 0.25f; }
    else       { y0 = (ky > 0) ? ky - 1 : 0; y1 = ky;       wy0 = 0.25f; wy1 = 0.75f; }
    if (x & 1) { x0 = kx; x1 = (kx + 1 < 32) ? kx + 1 : 31; wx0 = 0.75f; wx1 = 0.25f; }
    else       { x0 = (kx > 0) ? kx - 1 : 0; x1 = kx;       wx0 = 0.25f; wx1 = 0.75f; }
    float v = wy0 * (wx0 * row[y0 * 32 + x0] + wx1 * row[y0 * 32 + x1]) +
              wy1 * (wx0 * row[y1 * 32 + x0] + wx1 * row[y1 * 32 + x1]);
    orow[q] = v;
  }
}

// ---------------- launch -----------------------------------------------------
extern "C" void kernel_launch(void* const* d_in, const int* in_sizes, int n_in,
                              void* d_out, int out_size, void* d_ws, size_t ws_size,
                              hipStream_t stream) {
  const float* src1 = (const float*)d_in[0];  // [4,1024,64,64]
  const float* tar1 = (const float*)d_in[1];
  const float* src2 = (const float*)d_in[2];  // [4,2048,32,32]
  const float* tar2 = (const float*)d_in[3];
  float* out = (float*)d_out;                 // [4,6144,64,64] = 384 MiB

  // converted fp16-split tensors live in d_out's space as scratch (192 MiB),
  // fully overwritten by the epilogue afterwards.
  u8* scratch = (u8*)d_out;
  u8* c_src1 = scratch;                         // 64 MiB  [4,4096,32,128B]
  u8* c_tar1 = scratch + (64ull << 20);         // 64 MiB
  u8* c_src2 = scratch + (128ull << 20);        // 32 MiB  [4,1024,64,128B]
  u8* c_tar2 = scratch + (160ull << 20);        // 32 MiB

  float* hn1 = (float*)d_ws;          // 4*4096 f32
  float* hn2 = hn1 + 4 * 4096;        // 4*1024 f32
  u64* bk1 = (u64*)(hn2 + 4 * 1024);  // 4*4096 u64
  u64* bk2 = bk1 + 4 * 4096;          // 4*1024 u64

  split_convert<<<dim3(32, 16, 4), 256, 0, stream>>>(src1, c_src1, 1024, 4096);
  split_convert<<<dim3(32, 16, 4), 256, 0, stream>>>(tar1, c_tar1, 1024, 4096);
  split_convert<<<dim3(64, 4, 4), 256, 0, stream>>>(src2, c_src2, 2048, 1024);
  split_convert<<<dim3(64, 4, 4), 256, 0, stream>>>(tar2, c_tar2, 2048, 1024);

  hn_kernel<<<dim3(128, 4), 256, 0, stream>>>(tar1, hn1, 1024, 4096);
  hn_kernel<<<dim3(32, 4), 256, 0, stream>>>(tar2, hn2, 2048, 1024);
  hipMemsetAsync(bk1, 0xFF, (size_t)(4 * 4096 + 4 * 1024) * sizeof(u64), stream);

  // level 1: M=N=4096, K=1024 (Kc=32); tile 256x128; 16x32 m/n blocks
  nn_mfma8<8><<<2048, 512, 0, stream>>>(c_src1, c_tar1, hn1, bk1, 4096, 4096, 32, 16, 32);
  // level 2: M=N=1024, K=2048 (Kc=64); tile 128x128; 8x8 m/n blocks
  nn_mfma8<4><<<256, 512, 0, stream>>>(c_src2, c_tar2, hn2, bk2, 1024, 1024, 64, 8, 8);

  copy_src1<<<16384, 256, 0, stream>>>((const float4*)src1, (float4*)out);
  gather_nn1<<<dim3(1024, 4), 256, 0, stream>>>(tar1, bk1, out);
  upsample2<<<dim3(4096, 4), 256, 0, stream>>>(src2, tar2, bk2, out);
}

// Round 5
// 829.033 us; speedup vs baseline: 1.0928x; 1.0617x over previous
//
#include <hip/hip_runtime.h>
#include <cstdint>

using u8 = unsigned char;
using u64 = unsigned long long;

typedef _Float16 f16x8 __attribute__((ext_vector_type(8)));
typedef float f32x4 __attribute__((ext_vector_type(4)));

__device__ __forceinline__ void gload16(const void* g, void* l) {
  __builtin_amdgcn_global_load_lds((const __attribute__((address_space(1))) void*)g,
                                   (__attribute__((address_space(3))) void*)l, 16, 0, 0);
}

// ---- convert fp32 [B][C][N] -> packed fp16 split [B][N][C/32][hi 64B | lo 64B]
// lo is the exact residual scaled x4096 (dodges fp16 subnormals).
__global__ __launch_bounds__(256) void split_convert(const float* __restrict__ in,
                                                     u8* __restrict__ out,
                                                     int C, int N) {
  const int n = blockIdx.y * 256 + threadIdx.x;
  const int c0 = blockIdx.x * 32;
  const int b = blockIdx.z;
  const float* inB = in + (size_t)b * C * N;
  f16x8 hv[4], lv[4];
#pragma unroll
  for (int g = 0; g < 4; ++g)
#pragma unroll
    for (int e = 0; e < 8; ++e) {
      float x = inB[(size_t)(c0 + g * 8 + e) * N + n];
      _Float16 h = (_Float16)x;
      float r = (x - (float)h) * 4096.f;
      hv[g][e] = h;
      lv[g][e] = (_Float16)r;
    }
  const int Kc = C >> 5;
  u8* o = out + ((size_t)((size_t)b * N + n) * Kc + (c0 >> 5)) * 128;
#pragma unroll
  for (int g = 0; g < 4; ++g) {
    *(f16x8*)(o + g * 16) = hv[g];
    *(f16x8*)(o + 64 + g * 16) = lv[g];
  }
}

// ---- half-norms: hn[b][n] = 0.5 * sum_c t^2 ---------------------------------
__global__ __launch_bounds__(256) void hn_kernel(const float* __restrict__ tar,
                                                 float* __restrict__ hn,
                                                 int C, int N) {
  __shared__ float ps[256];
  int b = blockIdx.y;
  int nb = blockIdx.x * 32;
  int tn = threadIdx.x & 31, tg = threadIdx.x >> 5;
  const float* t = tar + (size_t)b * C * N + nb + tn;
  int cpg = C >> 3;
  int c0 = tg * cpg;
  float s = 0.f;
  for (int c = c0; c < c0 + cpg; ++c) {
    float v = t[(size_t)c * N];
    s = fmaf(v, v, s);
  }
  ps[threadIdx.x] = s;
  __syncthreads();
  if (threadIdx.x < 32) {
    float acc = 0.f;
#pragma unroll
    for (int g = 0; g < 8; ++g) acc += ps[g * 32 + threadIdx.x];
    hn[(size_t)b * N + nb + threadIdx.x] = 0.5f * acc;
  }
}

// ---- filter GEMM: f16-hi single pass, u16 quantized scores ------------------
// Tile 128x256, 512 threads (2x4 waves), wave tile 64x64, 3 LDS buffers,
// 2-deep prefetch, counted vmcnt. score_q = clamp((hn - dot_hi) * 64).
__global__ __launch_bounds__(512, 2) void nn_filter(
    const u8* __restrict__ Ac, const u8* __restrict__ Bc,
    const float* __restrict__ hn, unsigned short* __restrict__ sc,
    int M, int N, int Kc /* K/64 */, int mBlocks, int nBlocks) {
  constexpr int BM = 128, BN = 256;
  constexpr int ABYTES = BM * 128;          // 16 KB (64 k-f16 per row)
  constexpr int BUFSZ = (BM + BN) * 128;    // 48 KB
  __shared__ u8 smem[3 * BUFSZ];            // 144 KB

  const int tid = threadIdx.x;
  const int lane = tid & 63;
  const int wid = tid >> 6;
  const int wrow = wid >> 2;                // 0..1
  const int wcol = wid & 3;                 // 0..3
  const int lr = lane & 15, kh = lane >> 4;

  // XCD-bijective swizzle, n-group-of-4 inner (round-4 decode: FETCH 327MB)
  const int cpx = (int)gridDim.x >> 3;
  const int bid = (int)blockIdx.x;
  const int sbid = (bid & 7) * cpx + (bid >> 3);
  const int perB = mBlocks * nBlocks;
  const int b = sbid / perB;
  const int rr = sbid - b * perB;
  const int n1 = rr & 3;
  const int t2 = rr >> 2;
  const int mb = t2 % mBlocks;
  const int n2 = t2 / mBlocks;
  const int mbase = mb * BM;
  const int nbase = (n2 * 4 + n1) * BN;
  const size_t rstride = (size_t)Kc * 256;  // source row bytes (hi+lo)

  // staging: hi chunks only. thread (trow,tp): LDS slot tp holds source chunk
  // c = tp ^ (trow&7); source byte (within kt's 256B) = c*16 + ((c&4)<<4).
  const int trow = tid >> 3, tp = tid & 7;
  const int c_ = tp ^ (trow & 7);
  const int srcoff = (c_ << 4) + ((c_ & 4) << 4);
  const u8* aBase = Ac + ((size_t)b * M + mbase + trow) * rstride + srcoff;
  const u8* bBase = Bc + ((size_t)b * N + nbase + trow) * rstride + srcoff;

  const int swz = (lr & 7) << 4;
  const int h0_s = (kh << 4) ^ swz;          // k 0..31 quarter
  const int h1_s = ((kh + 4) << 4) ^ swz;    // k 32..63 quarter
  const int arow0 = (wrow * 64 + lr) * 128;
  const int brow0 = ABYTES + (wcol * 64 + lr) * 128;

  f32x4 acc[4][4];
#pragma unroll
  for (int i = 0; i < 4; ++i)
#pragma unroll
    for (int j = 0; j < 4; ++j) acc[i][j] = f32x4{0.f, 0.f, 0.f, 0.f};

  auto STAGE = [&](int kt, int p) {
    const u8* aS = aBase + (size_t)kt * 256;
    const u8* bS = bBase + (size_t)kt * 256;
    u8* dst = smem + p * BUFSZ + tid * 16;
#pragma unroll
    for (int v = 0; v < 2; ++v)
      gload16(aS + (size_t)v * 64 * rstride, dst + v * 8192);
#pragma unroll
    for (int w = 0; w < 4; ++w)
      gload16(bS + (size_t)w * 64 * rstride, dst + ABYTES + w * 8192);
  };

  STAGE(0, 0);
  STAGE(1, 1);
  int pcur = 0;
  for (int kt = 0; kt < Kc; ++kt) {
    int pn = pcur + 2; if (pn >= 3) pn -= 3;
    if (kt + 2 < Kc) STAGE(kt + 2, pn);
    if (kt + 2 < Kc)      asm volatile("s_waitcnt vmcnt(12)" ::: "memory");
    else if (kt + 1 < Kc) asm volatile("s_waitcnt vmcnt(6)" ::: "memory");
    else                  asm volatile("s_waitcnt vmcnt(0)" ::: "memory");
    __builtin_amdgcn_s_barrier();

    const u8* base = smem + pcur * BUFSZ;
    f16x8 a0[4], a1[4], b0[4], b1[4];
#pragma unroll
    for (int j = 0; j < 4; ++j) {
      b0[j] = *(const f16x8*)(base + brow0 + j * 2048 + h0_s);
      b1[j] = *(const f16x8*)(base + brow0 + j * 2048 + h1_s);
    }
#pragma unroll
    for (int i = 0; i < 4; ++i) {
      a0[i] = *(const f16x8*)(base + arow0 + i * 2048 + h0_s);
      a1[i] = *(const f16x8*)(base + arow0 + i * 2048 + h1_s);
    }
    __builtin_amdgcn_s_setprio(1);
#pragma unroll
    for (int i = 0; i < 4; ++i)
#pragma unroll
      for (int j = 0; j < 4; ++j) {
        acc[i][j] = __builtin_amdgcn_mfma_f32_16x16x32_f16(a0[i], b0[j], acc[i][j], 0, 0, 0);
        acc[i][j] = __builtin_amdgcn_mfma_f32_16x16x32_f16(a1[i], b1[j], acc[i][j], 0, 0, 0);
      }
    __builtin_amdgcn_s_setprio(0);
    asm volatile("" ::: "memory");
    __builtin_amdgcn_s_barrier();
    pcur = (pcur + 1 == 3) ? 0 : pcur + 1;
  }

  // epilogue: quantized score store. C/D layout col=lane&15, row=(lane>>4)*4+r
  const float* hnB = hn + (size_t)b * N;
  float hnv[4];
  int ncol[4];
#pragma unroll
  for (int j = 0; j < 4; ++j) {
    ncol[j] = nbase + wcol * 64 + j * 16 + lr;
    hnv[j] = hnB[ncol[j]];
  }
  unsigned short* scB = sc + (size_t)b * M * N;
#pragma unroll
  for (int i = 0; i < 4; ++i)
#pragma unroll
    for (int r = 0; r < 4; ++r) {
      const int m = mbase + wrow * 64 + i * 16 + kh * 4 + r;
      unsigned short* srow = scB + (size_t)m * N;
#pragma unroll
      for (int j = 0; j < 4; ++j) {
        float score = hnv[j] - acc[i][j][r];
        int qi = (int)(score * 64.0f);
        qi = qi < 0 ? 0 : (qi > 65535 ? 65535 : qi);
        srow[ncol[j]] = (unsigned short)qi;
      }
    }
}

// ---- select + exact rescore: one wave per source row ------------------------
// sweep 1: min of u16 scores; sweep 2: fp32-rescore all q <= min+64 (=1.0),
// pick strict-min in ascending n (matches jnp.argmin tie-break).
template <int K>
__global__ __launch_bounds__(256) void select_rescore(
    const unsigned short* __restrict__ sc, const u8* __restrict__ Ac,
    const u8* __restrict__ Bc, const float* __restrict__ hn,
    unsigned* __restrict__ idx, int M, int N) {
  const int w = threadIdx.x >> 6, lane = threadIdx.x & 63;
  const int row = blockIdx.x * 4 + w;
  const int b = blockIdx.y;
  const unsigned short* q = sc + ((size_t)b * M + row) * N;

  unsigned mn = 0xFFFFu;
  for (int i = lane * 4; i < N; i += 256) {
    ushort4 v = *(const ushort4*)(q + i);
    unsigned m1 = v.x < v.y ? v.x : v.y;
    unsigned m2 = v.z < v.w ? v.z : v.w;
    unsigned m3 = m1 < m2 ? m1 : m2;
    mn = m3 < mn ? m3 : mn;
  }
#pragma unroll
  for (int off = 32; off >= 1; off >>= 1) {
    unsigned o = (unsigned)__shfl_xor((int)mn, off);
    mn = o < mn ? o : mn;
  }
  const unsigned thr = mn + 64;

  constexpr int PER = K / 64;
  const float inv4096 = 2.44140625e-4f;
  float sv[PER];
  const u8* srow = Ac + ((size_t)b * M + row) * (size_t)(K * 4);
  const int ch = lane >> 5, pos = lane & 31;
#pragma unroll
  for (int i = 0; i < PER; ++i) {
    const u8* cptr = srow + (2 * i + ch) * 128;
    float hi = (float)*(const _Float16*)(cptr + pos * 2);
    float lo = (float)*(const _Float16*)(cptr + 64 + pos * 2);
    sv[i] = fmaf(lo, inv4096, hi);
  }

  float bestv = 3.4e38f;
  int bestn = 0;
  const u8* tbase = Bc + (size_t)b * N * (size_t)(K * 4);
  const float* hnB = hn + (size_t)b * N;
  for (int base = 0; base < N; base += 64) {
    unsigned v = q[base + lane];
    u64 mask = __ballot(v <= thr);
    while (mask) {
      int bit = __ffsll((long long)mask) - 1;
      mask &= mask - 1;
      int n = base + bit;
      const u8* trow = tbase + (size_t)n * (K * 4);
      float part = 0.f;
#pragma unroll
      for (int i = 0; i < PER; ++i) {
        const u8* cptr = trow + (2 * i + ch) * 128;
        float hi = (float)*(const _Float16*)(cptr + pos * 2);
        float lo = (float)*(const _Float16*)(cptr + 64 + pos * 2);
        part = fmaf(sv[i], fmaf(lo, inv4096, hi), part);
      }
#pragma unroll
      for (int off = 32; off >= 1; off >>= 1) part += __shfl_xor(part, off);
      float scf = hnB[n] - part;
      if (scf < bestv) { bestv = scf; bestn = n; }
    }
  }
  if (lane == 0) idx[(size_t)b * M + row] = (unsigned)bestn;
}

// ---------------- epilogue kernels -------------------------------------------
__global__ __launch_bounds__(256) void copy_src1(const float4* __restrict__ s,
                                                 float4* __restrict__ o) {
  size_t i = (size_t)blockIdx.x * 256 + threadIdx.x;
  size_t b = i >> 20;
  size_t r = i & ((1u << 20) - 1);
  o[b * (size_t)(6144 * 1024) + r] = s[i];
}

__global__ __launch_bounds__(256) void gather_nn1(const float* __restrict__ tar,
                                                  const unsigned* __restrict__ idx,
                                                  float* __restrict__ out) {
  int b = blockIdx.y, c = blockIdx.x;
  const float* trow = tar + ((size_t)b * 1024 + c) * 4096;
  const unsigned* ib = idx + (size_t)b * 4096;
  float* orow = out + ((size_t)b * 6144 + 1024 + c) * 4096;
  for (int p = threadIdx.x; p < 4096; p += 256) orow[p] = trow[ib[p]];
}

__global__ __launch_bounds__(256) void upsample2(const float* __restrict__ src2,
                                                 const float* __restrict__ tar2,
                                                 const unsigned* __restrict__ idx2,
                                                 float* __restrict__ out) {
  __shared__ float row[1024];
  int b = blockIdx.y, c = blockIdx.x;
  if (c < 2048) {
    const float* in = src2 + ((size_t)b * 2048 + c) * 1024;
    for (int p = threadIdx.x; p < 1024; p += 256) row[p] = in[p];
  } else {
    const float* trow = tar2 + ((size_t)b * 2048 + (c - 2048)) * 1024;
    const unsigned* ib = idx2 + (size_t)b * 1024;
    for (int p = threadIdx.x; p < 1024; p += 256) row[p] = trow[ib[p]];
  }
  __syncthreads();
  float* orow = out + ((size_t)b * 6144 + 2048 + c) * 4096;
  for (int q = threadIdx.x; q < 4096; q += 256) {
    int y = q >> 6, x = q & 63;
    int ky = y >> 1, kx = x >> 1;
    int y0, y1, x0, x1;
    float wy0, wy1, wx0, wx1;
    if (y & 1) { y0 = ky; y1 = (ky + 1 < 32) ? ky + 1 : 31; wy0 = 0.75f; wy1 = 0.25f; }
    else       { y0 = (ky > 0) ? ky - 1 : 0; y1 = ky;       wy0 = 0.25f; wy1 = 0.75f; }
    if (x & 1) { x0 = kx; x1 = (kx + 1 < 32) ? kx + 1 : 31; wx0 = 0.75f; wx1 = 0.25f; }
    else       { x0 = (kx > 0) ? kx - 1 : 0; x1 = kx;       wx0 = 0.25f; wx1 = 0.75f; }
    float v = wy0 * (wx0 * row[y0 * 32 + x0] + wx1 * row[y0 * 32 + x1]) +
              wy1 * (wx0 * row[y1 * 32 + x0] + wx1 * row[y1 * 32 + x1]);
    orow[q] = v;
  }
}

// ---------------- launch -----------------------------------------------------
extern "C" void kernel_launch(void* const* d_in, const int* in_sizes, int n_in,
                              void* d_out, int out_size, void* d_ws, size_t ws_size,
                              hipStream_t stream) {
  const float* src1 = (const float*)d_in[0];  // [4,1024,64,64]
  const float* tar1 = (const float*)d_in[1];
  const float* src2 = (const float*)d_in[2];  // [4,2048,32,32]
  const float* tar2 = (const float*)d_in[3];
  float* out = (float*)d_out;                 // [4,6144,64,64] = 384 MiB

  // scratch in d_out (fully overwritten by epilogue):
  u8* scratch = (u8*)d_out;
  u8* c_src1 = scratch;                         // 64 MiB  split [4,4096,32,128B]
  u8* c_tar1 = scratch + (64ull << 20);         // 64 MiB
  u8* c_src2 = scratch + (128ull << 20);        // 32 MiB  split [4,1024,64,128B]
  u8* c_tar2 = scratch + (160ull << 20);        // 32 MiB
  unsigned short* sc1 = (unsigned short*)(scratch + (192ull << 20));  // 128 MiB
  unsigned short* sc2 = (unsigned short*)(scratch + (320ull << 20));  // 8 MiB

  float* hn1 = (float*)d_ws;              // 4*4096 f32
  float* hn2 = hn1 + 4 * 4096;            // 4*1024 f32
  unsigned* idx1 = (unsigned*)(hn2 + 4 * 1024);  // 4*4096 u32
  unsigned* idx2 = idx1 + 4 * 4096;              // 4*1024 u32

  split_convert<<<dim3(32, 16, 4), 256, 0, stream>>>(src1, c_src1, 1024, 4096);
  split_convert<<<dim3(32, 16, 4), 256, 0, stream>>>(tar1, c_tar1, 1024, 4096);
  split_convert<<<dim3(64, 4, 4), 256, 0, stream>>>(src2, c_src2, 2048, 1024);
  split_convert<<<dim3(64, 4, 4), 256, 0, stream>>>(tar2, c_tar2, 2048, 1024);

  hn_kernel<<<dim3(128, 4), 256, 0, stream>>>(tar1, hn1, 1024, 4096);
  hn_kernel<<<dim3(32, 4), 256, 0, stream>>>(tar2, hn2, 2048, 1024);

  // level 1: M=N=4096, K=1024 (Kc=16); 32x16 m/n blocks -> 2048
  nn_filter<<<2048, 512, 0, stream>>>(c_src1, c_tar1, hn1, sc1, 4096, 4096, 16, 32, 16);
  // level 2: M=N=1024, K=2048 (Kc=32); 8x4 m/n blocks -> 128
  nn_filter<<<128, 512, 0, stream>>>(c_src2, c_tar2, hn2, sc2, 1024, 1024, 32, 8, 4);

  select_rescore<1024><<<dim3(1024, 4), 256, 0, stream>>>(sc1, c_src1, c_tar1, hn1, idx1, 4096, 4096);
  select_rescore<2048><<<dim3(256, 4), 256, 0, stream>>>(sc2, c_src2, c_tar2, hn2, idx2, 1024, 1024);

  copy_src1<<<16384, 256, 0, stream>>>((const float4*)src1, (float4*)out);
  gather_nn1<<<dim3(1024, 4), 256, 0, stream>>>(tar1, idx1, out);
  upsample2<<<dim3(4096, 4), 256, 0, stream>>>(src2, tar2, idx2, out);
}

// Round 6
// 757.120 us; speedup vs baseline: 1.1966x; 1.0950x over previous
//
#include <hip/hip_runtime.h>
#include <cstdint>

using u8 = unsigned char;
using u64 = unsigned long long;

typedef _Float16 f16x8 __attribute__((ext_vector_type(8)));
typedef float f32x4 __attribute__((ext_vector_type(4)));

__device__ __forceinline__ void gload16(const void* g, void* l) {
  __builtin_amdgcn_global_load_lds((const __attribute__((address_space(1))) void*)g,
                                   (__attribute__((address_space(3))) void*)l, 16, 0, 0);
}

#define VMCNT(N) asm volatile("s_waitcnt vmcnt(" #N ")" ::: "memory")

// ---- convert fp32 [B][C][N] -> dense fp16 planes hi[B][N][C], lo[B][N][C] ---
// lo = exact residual scaled x4096 (dodges fp16 subnormals).
__global__ __launch_bounds__(256) void split_convert(const float* __restrict__ in,
                                                     _Float16* __restrict__ hi,
                                                     _Float16* __restrict__ lo,
                                                     int C, int N) {
  const int n = blockIdx.y * 256 + threadIdx.x;
  const int c0 = blockIdx.x * 32;
  const int b = blockIdx.z;
  const float* inB = in + (size_t)b * C * N;
  f16x8 hv[4], lv[4];
#pragma unroll
  for (int g = 0; g < 4; ++g)
#pragma unroll
    for (int e = 0; e < 8; ++e) {
      float x = inB[(size_t)(c0 + g * 8 + e) * N + n];
      _Float16 h = (_Float16)x;
      float r = (x - (float)h) * 4096.f;
      hv[g][e] = h;
      lv[g][e] = (_Float16)r;
    }
  _Float16* oh = hi + ((size_t)b * N + n) * C + c0;
  _Float16* ol = lo + ((size_t)b * N + n) * C + c0;
#pragma unroll
  for (int g = 0; g < 4; ++g) {
    *(f16x8*)(oh + g * 8) = hv[g];
    *(f16x8*)(ol + g * 8) = lv[g];
  }
}

// ---- half-norms: hn[b][n] = 0.5 * sum_c t^2 ---------------------------------
__global__ __launch_bounds__(256) void hn_kernel(const float* __restrict__ tar,
                                                 float* __restrict__ hn,
                                                 int C, int N) {
  __shared__ float ps[256];
  int b = blockIdx.y;
  int nb = blockIdx.x * 32;
  int tn = threadIdx.x & 31, tg = threadIdx.x >> 5;
  const float* t = tar + (size_t)b * C * N + nb + tn;
  int cpg = C >> 3;
  int c0 = tg * cpg;
  float s = 0.f;
  for (int c = c0; c < c0 + cpg; ++c) {
    float v = t[(size_t)c * N];
    s = fmaf(v, v, s);
  }
  ps[threadIdx.x] = s;
  __syncthreads();
  if (threadIdx.x < 32) {
    float acc = 0.f;
#pragma unroll
    for (int g = 0; g < 8; ++g) acc += ps[g * 32 + threadIdx.x];
    hn[(size_t)b * N + nb + threadIdx.x] = 0.5f * acc;
  }
}

// ---- filter GEMM, m201-style phase schedule ---------------------------------
// Tile BM=BN=32*MI (wave grid 2 x WCN, wave tile MI*16 x NJ*16), BK=64.
// LDS: 4 chunks = 2 dbuf x 2 k-half, chunk = A(BM x 32k) + B(BN x 32k).
// Per K-tile: 2*G phases, each {ds subtile; stage 1 half; vmcnt; bar; lgkm0;
// setprio; 16 MFMA; setprio; bar}. score_q = clamp((hn - dot_hi)*64) u16.
#define MFMA_BLOCK(GI)                                                         \
  __builtin_amdgcn_s_barrier();                                                \
  asm volatile("s_waitcnt lgkmcnt(0)" ::: "memory");                           \
  __builtin_amdgcn_sched_barrier(0);                                           \
  __builtin_amdgcn_s_setprio(1);                                               \
  _Pragma("unroll") for (int i2 = 0; i2 < 4; ++i2)                             \
      _Pragma("unroll") for (int j = 0; j < NJ; ++j) acc[(GI)*4 + i2][j] =     \
      __builtin_amdgcn_mfma_f32_16x16x32_f16(av[i2], bv[j],                    \
                                             acc[(GI)*4 + i2][j], 0, 0, 0);    \
  __builtin_amdgcn_s_setprio(0);                                               \
  asm volatile("" ::: "memory");                                               \
  __builtin_amdgcn_s_barrier();

template <int MI, int NJ, int WCN, int NTH>
__global__ __launch_bounds__(NTH, 2) void nn_filter8(
    const u8* __restrict__ Ahi, const u8* __restrict__ Bhi,
    const float* __restrict__ hn, unsigned short* __restrict__ sc,
    int M, int N, int NT /* K/64 */, int mBlocks, int nBlocks) {
  constexpr int BM = 2 * MI * 16;        // == BN for our configs
  constexpr int G = MI / 4;              // phases per k-half
  constexpr int CHUNK_A = BM * 64;
  constexpr int CHUNK = 2 * CHUNK_A;
  __shared__ u8 smem[4 * CHUNK];

  const int tid = threadIdx.x;
  const int lane = tid & 63;
  const int wid = tid >> 6;
  const int wrow = wid / WCN;            // 0..1
  const int wcol = wid % WCN;
  const int lr = lane & 15, kh = lane >> 4;

  // XCD-bijective swizzle, n-group-of-4 inner
  const int cpx = (int)gridDim.x >> 3;
  const int bid = (int)blockIdx.x;
  const int sbid = (bid & 7) * cpx + (bid >> 3);
  const int perB = mBlocks * nBlocks;
  const int b = sbid / perB;
  const int rr = sbid - b * perB;
  const int n1 = rr & 3;
  const int t2 = rr >> 2;
  const int mb = t2 % mBlocks;
  const int n2 = t2 / mBlocks;
  const int mbase = mb * BM;
  const int nbase = (n2 * 4 + n1) * BM;
  const size_t rstride = (size_t)NT * 128;  // source row bytes (hi plane)

  // staging ptrs: thread covers rows r0 and r0+NTH/4, source chunk pre-swizzled
  const int r0 = (tid >> 6) * 16 + ((tid & 63) >> 2);
  const int sA = ((lane & 3) ^ (r0 >> 1)) & 3;
  const u8* aP0 = Ahi + ((size_t)b * M + mbase + r0) * rstride + sA * 16;
  const u8* aP1 = aP0 + (size_t)(NTH / 4) * rstride;
  const u8* bP0 = Bhi + ((size_t)b * N + nbase + r0) * rstride + sA * 16;
  const u8* bP1 = bP0 + (size_t)(NTH / 4) * rstride;

  auto STAGE = [&](int X, int h) {
    const size_t ko = (size_t)X * 128 + h * 64;
    u8* cb = smem + ((X & 1) * 2 + h) * CHUNK;
    gload16(aP0 + ko, cb + tid * 16);
    gload16(aP1 + ko, cb + NTH * 16 + tid * 16);
    gload16(bP0 + ko, cb + CHUNK_A + tid * 16);
    gload16(bP1 + ko, cb + CHUNK_A + NTH * 16 + tid * 16);
  };

  // ds offsets (swizzled to match staged layout)
  int a_off[MI], b_off[NJ];
#pragma unroll
  for (int i = 0; i < MI; ++i) {
    const int row = wrow * (MI * 16) + i * 16 + lr;
    a_off[i] = row * 64 + (((kh ^ (row >> 1)) & 3) << 4);
  }
#pragma unroll
  for (int j = 0; j < NJ; ++j) {
    const int row = wcol * (NJ * 16) + j * 16 + lr;
    b_off[j] = CHUNK_A + row * 64 + (((kh ^ (row >> 1)) & 3) << 4);
  }

  f32x4 acc[MI][NJ];
#pragma unroll
  for (int i = 0; i < MI; ++i)
#pragma unroll
    for (int j = 0; j < NJ; ++j) acc[i][j] = f32x4{0.f, 0.f, 0.f, 0.f};

  // prologue: 3 half-chunks in flight, wait the first, sync
  STAGE(0, 0);
  STAGE(0, 1);
  STAGE(1, 0);
  VMCNT(8);
  __builtin_amdgcn_s_barrier();

  for (int X = 0; X < NT; ++X) {
    const u8* cb0 = smem + ((X & 1) * 2) * CHUNK;
    const u8* cb1 = cb0 + CHUNK;
    f16x8 av[4], bv[NJ];

    // ---- phase (h0, g0) ----
#pragma unroll
    for (int j = 0; j < NJ; ++j) bv[j] = *(const f16x8*)(cb0 + b_off[j]);
#pragma unroll
    for (int i2 = 0; i2 < 4; ++i2) av[i2] = *(const f16x8*)(cb0 + a_off[i2]);
    if (X + 1 < NT) STAGE(X + 1, 1);
    if constexpr (G == 1) {
      if (X + 1 < NT) { VMCNT(8); } else { VMCNT(0); }
    }
    MFMA_BLOCK(0)

    if constexpr (G == 2) {
      // ---- phase (h0, g1): guard chunk (X,h1) ----
#pragma unroll
      for (int i2 = 0; i2 < 4; ++i2) av[i2] = *(const f16x8*)(cb0 + a_off[4 + i2]);
      if (X + 1 < NT) { VMCNT(8); } else { VMCNT(0); }
      MFMA_BLOCK(1)
    }

    // ---- phase (h1, g0) ----
#pragma unroll
    for (int j = 0; j < NJ; ++j) bv[j] = *(const f16x8*)(cb1 + b_off[j]);
#pragma unroll
    for (int i2 = 0; i2 < 4; ++i2) av[i2] = *(const f16x8*)(cb1 + a_off[i2]);
    if (X + 2 < NT) STAGE(X + 2, 0);
    if constexpr (G == 1) {
      if (X + 1 < NT) {
        if (X + 2 < NT) { VMCNT(8); } else { VMCNT(4); }
      }
    }
    MFMA_BLOCK(0)

    if constexpr (G == 2) {
      // ---- phase (h1, g1): guard chunk (X+1,h0) ----
#pragma unroll
      for (int i2 = 0; i2 < 4; ++i2) av[i2] = *(const f16x8*)(cb1 + a_off[4 + i2]);
      if (X + 1 < NT) {
        if (X + 2 < NT) { VMCNT(8); } else { VMCNT(4); }
      }
      MFMA_BLOCK(1)
    }
  }

  // epilogue: quantized score store. C/D: col=lane&15, row=(lane>>4)*4+r
  const float* hnB = hn + (size_t)b * N;
  float hnv[NJ];
  int ncol[NJ];
#pragma unroll
  for (int j = 0; j < NJ; ++j) {
    ncol[j] = nbase + wcol * (NJ * 16) + j * 16 + lr;
    hnv[j] = hnB[ncol[j]];
  }
  unsigned short* scB = sc + (size_t)b * M * N;
#pragma unroll
  for (int i = 0; i < MI; ++i)
#pragma unroll
    for (int r = 0; r < 4; ++r) {
      const int m = mbase + wrow * (MI * 16) + i * 16 + kh * 4 + r;
      unsigned short* srow = scB + (size_t)m * N;
#pragma unroll
      for (int j = 0; j < NJ; ++j) {
        float score = hnv[j] - acc[i][j][r];
        int qi = (int)(score * 64.0f);
        qi = qi < 0 ? 0 : (qi > 65535 ? 65535 : qi);
        srow[ncol[j]] = (unsigned short)qi;
      }
    }
}

// ---- select + exact rescore: one wave per source row ------------------------
template <int K>
__global__ __launch_bounds__(256) void select_rescore(
    const unsigned short* __restrict__ sc,
    const _Float16* __restrict__ hiA, const _Float16* __restrict__ loA,
    const _Float16* __restrict__ hiB, const _Float16* __restrict__ loB,
    const float* __restrict__ hn, unsigned* __restrict__ idx, int M, int N) {
  const int w = threadIdx.x >> 6, lane = threadIdx.x & 63;
  const int row = blockIdx.x * 4 + w;
  const int b = blockIdx.y;
  const unsigned short* q = sc + ((size_t)b * M + row) * N;

  unsigned mn = 0xFFFFu;
  for (int i = lane * 4; i < N; i += 256) {
    ushort4 v = *(const ushort4*)(q + i);
    unsigned m1 = v.x < v.y ? v.x : v.y;
    unsigned m2 = v.z < v.w ? v.z : v.w;
    unsigned m3 = m1 < m2 ? m1 : m2;
    mn = m3 < mn ? m3 : mn;
  }
#pragma unroll
  for (int off = 32; off >= 1; off >>= 1) {
    unsigned o = (unsigned)__shfl_xor((int)mn, off);
    mn = o < mn ? o : mn;
  }
  const unsigned thr = mn + 64;

  constexpr int PER = K / 64;
  const float inv = 2.44140625e-4f;
  float sv[PER];
  const _Float16* hA = hiA + ((size_t)b * M + row) * K;
  const _Float16* lA = loA + ((size_t)b * M + row) * K;
#pragma unroll
  for (int i = 0; i < PER; ++i)
    sv[i] = fmaf((float)lA[i * 64 + lane], inv, (float)hA[i * 64 + lane]);

  float bestv = 3.4e38f;
  int bestn = 0;
  const float* hnB = hn + (size_t)b * N;
  for (int base = 0; base < N; base += 64) {
    unsigned v = q[base + lane];
    u64 mask = __ballot(v <= thr);
    while (mask) {
      int bit = __ffsll((long long)mask) - 1;
      mask &= mask - 1;
      int n = base + bit;
      const _Float16* hB = hiB + ((size_t)b * N + n) * K;
      const _Float16* lB = loB + ((size_t)b * N + n) * K;
      float part = 0.f;
#pragma unroll
      for (int i = 0; i < PER; ++i)
        part = fmaf(sv[i], fmaf((float)lB[i * 64 + lane], inv, (float)hB[i * 64 + lane]), part);
#pragma unroll
      for (int off = 32; off >= 1; off >>= 1) part += __shfl_xor(part, off);
      float scf = hnB[n] - part;
      if (scf < bestv) { bestv = scf; bestn = n; }
    }
  }
  if (lane == 0) idx[(size_t)b * M + row] = (unsigned)bestn;
}

// ---------------- epilogue kernels -------------------------------------------
__global__ __launch_bounds__(256) void copy_src1(const float4* __restrict__ s,
                                                 float4* __restrict__ o) {
  size_t i = (size_t)blockIdx.x * 256 + threadIdx.x;
  size_t b = i >> 20;
  size_t r = i & ((1u << 20) - 1);
  o[b * (size_t)(6144 * 1024) + r] = s[i];
}

__global__ __launch_bounds__(256) void gather_nn1(const float* __restrict__ tar,
                                                  const unsigned* __restrict__ idx,
                                                  float* __restrict__ out) {
  int b = blockIdx.y, c = blockIdx.x;
  const float* trow = tar + ((size_t)b * 1024 + c) * 4096;
  const unsigned* ib = idx + (size_t)b * 4096;
  float* orow = out + ((size_t)b * 6144 + 1024 + c) * 4096;
  for (int p = threadIdx.x; p < 4096; p += 256) orow[p] = trow[ib[p]];
}

__global__ __launch_bounds__(256) void upsample2(const float* __restrict__ src2,
                                                 const float* __restrict__ tar2,
                                                 const unsigned* __restrict__ idx2,
                                                 float* __restrict__ out) {
  __shared__ float row[1024];
  int b = blockIdx.y, c = blockIdx.x;
  if (c < 2048) {
    const float* in = src2 + ((size_t)b * 2048 + c) * 1024;
    for (int p = threadIdx.x; p < 1024; p += 256) row[p] = in[p];
  } else {
    const float* trow = tar2 + ((size_t)b * 2048 + (c - 2048)) * 1024;
    const unsigned* ib = idx2 + (size_t)b * 1024;
    for (int p = threadIdx.x; p < 1024; p += 256) row[p] = trow[ib[p]];
  }
  __syncthreads();
  float* orow = out + ((size_t)b * 6144 + 2048 + c) * 4096;
  for (int q = threadIdx.x; q < 4096; q += 256) {
    int y = q >> 6, x = q & 63;
    int ky = y >> 1, kx = x >> 1;
    int y0, y1, x0, x1;
    float wy0, wy1, wx0, wx1;
    if (y & 1) { y0 = ky; y1 = (ky + 1 < 32) ? ky + 1 : 31; wy0 = 0.75f; wy1 = 0.25f; }
    else       { y0 = (ky > 0) ? ky - 1 : 0; y1 = ky;       wy0 = 0.25f; wy1 = 0.75f; }
    if (x & 1) { x0 = kx; x1 = (kx + 1 < 32) ? kx + 1 : 31; wx0 = 0.75f; wx1 = 0.25f; }
    else       { x0 = (kx > 0) ? kx - 1 : 0; x1 = kx;       wx0 = 0.25f; wx1 = 0.75f; }
    float v = wy0 * (wx0 * row[y0 * 32 + x0] + wx1 * row[y0 * 32 + x1]) +
              wy1 * (wx0 * row[y1 * 32 + x0] + wx1 * row[y1 * 32 + x1]);
    orow[q] = v;
  }
}

// ---------------- launch -----------------------------------------------------
extern "C" void kernel_launch(void* const* d_in, const int* in_sizes, int n_in,
                              void* d_out, int out_size, void* d_ws, size_t ws_size,
                              hipStream_t stream) {
  const float* src1 = (const float*)d_in[0];  // [4,1024,64,64]
  const float* tar1 = (const float*)d_in[1];
  const float* src2 = (const float*)d_in[2];  // [4,2048,32,32]
  const float* tar2 = (const float*)d_in[3];
  float* out = (float*)d_out;                 // [4,6144,64,64] = 384 MiB

  // scratch in d_out (fully overwritten by epilogue):
  u8* scratch = (u8*)d_out;
  _Float16* hi1s = (_Float16*)scratch;                       // 32 MiB [4,4096,1024]
  _Float16* lo1s = (_Float16*)(scratch + (32ull << 20));     // 32 MiB
  _Float16* hi1t = (_Float16*)(scratch + (64ull << 20));     // 32 MiB
  _Float16* lo1t = (_Float16*)(scratch + (96ull << 20));     // 32 MiB
  _Float16* hi2s = (_Float16*)(scratch + (128ull << 20));    // 16 MiB [4,1024,2048]
  _Float16* lo2s = (_Float16*)(scratch + (144ull << 20));    // 16 MiB
  _Float16* hi2t = (_Float16*)(scratch + (160ull << 20));    // 16 MiB
  _Float16* lo2t = (_Float16*)(scratch + (176ull << 20));    // 16 MiB
  unsigned short* sc1 = (unsigned short*)(scratch + (192ull << 20));  // 128 MiB
  unsigned short* sc2 = (unsigned short*)(scratch + (320ull << 20));  // 8 MiB

  float* hn1 = (float*)d_ws;              // 4*4096 f32
  float* hn2 = hn1 + 4 * 4096;            // 4*1024 f32
  unsigned* idx1 = (unsigned*)(hn2 + 4 * 1024);  // 4*4096 u32
  unsigned* idx2 = idx1 + 4 * 4096;              // 4*1024 u32

  split_convert<<<dim3(32, 16, 4), 256, 0, stream>>>(src1, hi1s, lo1s, 1024, 4096);
  split_convert<<<dim3(32, 16, 4), 256, 0, stream>>>(tar1, hi1t, lo1t, 1024, 4096);
  split_convert<<<dim3(64, 4, 4), 256, 0, stream>>>(src2, hi2s, lo2s, 2048, 1024);
  split_convert<<<dim3(64, 4, 4), 256, 0, stream>>>(tar2, hi2t, lo2t, 2048, 1024);

  hn_kernel<<<dim3(128, 4), 256, 0, stream>>>(tar1, hn1, 1024, 4096);
  hn_kernel<<<dim3(32, 4), 256, 0, stream>>>(tar2, hn2, 2048, 1024);

  // level 1: 256x256 tile, M=N=4096, K=1024 (NT=16); 16x16 blocks x4 = 1024
  nn_filter8<8, 4, 4, 512><<<1024, 512, 0, stream>>>(
      (const u8*)hi1s, (const u8*)hi1t, hn1, sc1, 4096, 4096, 16, 16, 16);
  // level 2: 128x128 tile, M=N=1024, K=2048 (NT=32); 8x8 blocks x4 = 256
  nn_filter8<4, 4, 2, 256><<<256, 256, 0, stream>>>(
      (const u8*)hi2s, (const u8*)hi2t, hn2, sc2, 1024, 1024, 32, 8, 8);

  select_rescore<1024><<<dim3(1024, 4), 256, 0, stream>>>(
      sc1, hi1s, lo1s, hi1t, lo1t, hn1, idx1, 4096, 4096);
  select_rescore<2048><<<dim3(256, 4), 256, 0, stream>>>(
      sc2, hi2s, lo2s, hi2t, lo2t, hn2, idx2, 1024, 1024);

  copy_src1<<<16384, 256, 0, stream>>>((const float4*)src1, (float4*)out);
  gather_nn1<<<dim3(1024, 4), 256, 0, stream>>>(tar1, idx1, out);
  upsample2<<<dim3(4096, 4), 256, 0, stream>>>(src2, tar2, idx2, out);
}

// Round 7
// 570.118 us; speedup vs baseline: 1.5891x; 1.3280x over previous
//
#include <hip/hip_runtime.h>
#include <cstdint>

using u8 = unsigned char;
using u64 = unsigned long long;

typedef _Float16 f16x8 __attribute__((ext_vector_type(8)));
typedef float f32x4 __attribute__((ext_vector_type(4)));
typedef unsigned short u16x8 __attribute__((ext_vector_type(8)));

__device__ __forceinline__ void gload16(const void* g, void* l) {
  __builtin_amdgcn_global_load_lds((const __attribute__((address_space(1))) void*)g,
                                   (__attribute__((address_space(3))) void*)l, 16, 0, 0);
}

#define VMCNT(N) asm volatile("s_waitcnt vmcnt(" #N ")" ::: "memory")

// ---- convert fp32 [B][C][N] -> dense fp16 planes hi[B][N][C], lo[B][N][C] ---
// lo = exact residual scaled x4096. Optionally emits per-c-chunk partial
// sum-of-squares (deterministic) for hn.
template <bool WITH_HN>
__global__ __launch_bounds__(256) void split_convert(const float* __restrict__ in,
                                                     _Float16* __restrict__ hi,
                                                     _Float16* __restrict__ lo,
                                                     float* __restrict__ hnp,
                                                     int C, int N) {
  const int n = blockIdx.y * 256 + threadIdx.x;
  const int c0 = blockIdx.x * 32;
  const int b = blockIdx.z;
  const float* inB = in + (size_t)b * C * N;
  f16x8 hv[4], lv[4];
  float ss = 0.f;
#pragma unroll
  for (int g = 0; g < 4; ++g)
#pragma unroll
    for (int e = 0; e < 8; ++e) {
      float x = inB[(size_t)(c0 + g * 8 + e) * N + n];
      _Float16 h = (_Float16)x;
      float r = (x - (float)h) * 4096.f;
      hv[g][e] = h;
      lv[g][e] = (_Float16)r;
      if (WITH_HN) ss = fmaf(x, x, ss);
    }
  _Float16* oh = hi + ((size_t)b * N + n) * C + c0;
  _Float16* ol = lo + ((size_t)b * N + n) * C + c0;
#pragma unroll
  for (int g = 0; g < 4; ++g) {
    *(f16x8*)(oh + g * 8) = hv[g];
    *(f16x8*)(ol + g * 8) = lv[g];
  }
  if (WITH_HN)
    hnp[((size_t)b * gridDim.x + blockIdx.x) * N + n] = ss;
}

// ---- hn[b][n] = 0.5 * sum over chunks of hnp --------------------------------
__global__ __launch_bounds__(256) void hn_reduce(const float* __restrict__ hnp,
                                                 float* __restrict__ hn,
                                                 int NC, int N) {
  const int n = blockIdx.x * 256 + threadIdx.x;
  const int b = blockIdx.y;
  float acc = 0.f;
  for (int cc = 0; cc < NC; ++cc) acc += hnp[((size_t)b * NC + cc) * N + n];
  hn[(size_t)b * N + n] = 0.5f * acc;
}

// ---- filter GEMM, phase schedule (unchanged from round 6 — validated) -------
#define MFMA_BLOCK(GI)                                                         \
  __builtin_amdgcn_s_barrier();                                                \
  asm volatile("s_waitcnt lgkmcnt(0)" ::: "memory");                           \
  __builtin_amdgcn_sched_barrier(0);                                           \
  __builtin_amdgcn_s_setprio(1);                                               \
  _Pragma("unroll") for (int i2 = 0; i2 < 4; ++i2)                             \
      _Pragma("unroll") for (int j = 0; j < NJ; ++j) acc[(GI)*4 + i2][j] =     \
      __builtin_amdgcn_mfma_f32_16x16x32_f16(av[i2], bv[j],                    \
                                             acc[(GI)*4 + i2][j], 0, 0, 0);    \
  __builtin_amdgcn_s_setprio(0);                                               \
  asm volatile("" ::: "memory");                                               \
  __builtin_amdgcn_s_barrier();

template <int MI, int NJ, int WCN, int NTH>
__global__ __launch_bounds__(NTH, 2) void nn_filter8(
    const u8* __restrict__ Ahi, const u8* __restrict__ Bhi,
    const float* __restrict__ hn, unsigned short* __restrict__ sc,
    int M, int N, int NT /* K/64 */, int mBlocks, int nBlocks) {
  constexpr int BM = 2 * MI * 16;
  constexpr int G = MI / 4;
  constexpr int CHUNK_A = BM * 64;
  constexpr int CHUNK = 2 * CHUNK_A;
  __shared__ u8 smem[4 * CHUNK];

  const int tid = threadIdx.x;
  const int lane = tid & 63;
  const int wid = tid >> 6;
  const int wrow = wid / WCN;
  const int wcol = wid % WCN;
  const int lr = lane & 15, kh = lane >> 4;

  const int cpx = (int)gridDim.x >> 3;
  const int bid = (int)blockIdx.x;
  const int sbid = (bid & 7) * cpx + (bid >> 3);
  const int perB = mBlocks * nBlocks;
  const int b = sbid / perB;
  const int rr = sbid - b * perB;
  const int n1 = rr & 3;
  const int t2 = rr >> 2;
  const int mb = t2 % mBlocks;
  const int n2 = t2 / mBlocks;
  const int mbase = mb * BM;
  const int nbase = (n2 * 4 + n1) * BM;
  const size_t rstride = (size_t)NT * 128;

  const int r0 = (tid >> 6) * 16 + ((tid & 63) >> 2);
  const int sA = ((lane & 3) ^ (r0 >> 1)) & 3;
  const u8* aP0 = Ahi + ((size_t)b * M + mbase + r0) * rstride + sA * 16;
  const u8* aP1 = aP0 + (size_t)(NTH / 4) * rstride;
  const u8* bP0 = Bhi + ((size_t)b * N + nbase + r0) * rstride + sA * 16;
  const u8* bP1 = bP0 + (size_t)(NTH / 4) * rstride;

  auto STAGE = [&](int X, int h) {
    const size_t ko = (size_t)X * 128 + h * 64;
    u8* cb = smem + ((X & 1) * 2 + h) * CHUNK;
    gload16(aP0 + ko, cb + tid * 16);
    gload16(aP1 + ko, cb + NTH * 16 + tid * 16);
    gload16(bP0 + ko, cb + CHUNK_A + tid * 16);
    gload16(bP1 + ko, cb + CHUNK_A + NTH * 16 + tid * 16);
  };

  int a_off[MI], b_off[NJ];
#pragma unroll
  for (int i = 0; i < MI; ++i) {
    const int row = wrow * (MI * 16) + i * 16 + lr;
    a_off[i] = row * 64 + (((kh ^ (row >> 1)) & 3) << 4);
  }
#pragma unroll
  for (int j = 0; j < NJ; ++j) {
    const int row = wcol * (NJ * 16) + j * 16 + lr;
    b_off[j] = CHUNK_A + row * 64 + (((kh ^ (row >> 1)) & 3) << 4);
  }

  f32x4 acc[MI][NJ];
#pragma unroll
  for (int i = 0; i < MI; ++i)
#pragma unroll
    for (int j = 0; j < NJ; ++j) acc[i][j] = f32x4{0.f, 0.f, 0.f, 0.f};

  STAGE(0, 0);
  STAGE(0, 1);
  STAGE(1, 0);
  VMCNT(8);
  __builtin_amdgcn_s_barrier();

  for (int X = 0; X < NT; ++X) {
    const u8* cb0 = smem + ((X & 1) * 2) * CHUNK;
    const u8* cb1 = cb0 + CHUNK;
    f16x8 av[4], bv[NJ];

#pragma unroll
    for (int j = 0; j < NJ; ++j) bv[j] = *(const f16x8*)(cb0 + b_off[j]);
#pragma unroll
    for (int i2 = 0; i2 < 4; ++i2) av[i2] = *(const f16x8*)(cb0 + a_off[i2]);
    if (X + 1 < NT) STAGE(X + 1, 1);
    if (X + 1 < NT) { VMCNT(8); } else { VMCNT(0); }
    MFMA_BLOCK(0)

    if constexpr (G == 2) {
#pragma unroll
      for (int i2 = 0; i2 < 4; ++i2) av[i2] = *(const f16x8*)(cb0 + a_off[4 + i2]);
      MFMA_BLOCK(1)
    }

#pragma unroll
    for (int j = 0; j < NJ; ++j) bv[j] = *(const f16x8*)(cb1 + b_off[j]);
#pragma unroll
    for (int i2 = 0; i2 < 4; ++i2) av[i2] = *(const f16x8*)(cb1 + a_off[i2]);
    if (X + 2 < NT) STAGE(X + 2, 0);
    if (X + 1 < NT) {
      if (X + 2 < NT) { VMCNT(8); } else { VMCNT(4); }
    }
    MFMA_BLOCK(0)

    if constexpr (G == 2) {
#pragma unroll
      for (int i2 = 0; i2 < 4; ++i2) av[i2] = *(const f16x8*)(cb1 + a_off[4 + i2]);
      MFMA_BLOCK(1)
    }
  }

  const float* hnB = hn + (size_t)b * N;
  float hnv[NJ];
  int ncol[NJ];
#pragma unroll
  for (int j = 0; j < NJ; ++j) {
    ncol[j] = nbase + wcol * (NJ * 16) + j * 16 + lr;
    hnv[j] = hnB[ncol[j]];
  }
  unsigned short* scB = sc + (size_t)b * M * N;
#pragma unroll
  for (int i = 0; i < MI; ++i)
#pragma unroll
    for (int r = 0; r < 4; ++r) {
      const int m = mbase + wrow * (MI * 16) + i * 16 + kh * 4 + r;
      unsigned short* srow = scB + (size_t)m * N;
#pragma unroll
      for (int j = 0; j < NJ; ++j) {
        float score = hnv[j] - acc[i][j][r];
        int qi = (int)(score * 64.0f);
        qi = qi < 0 ? 0 : (qi > 65535 ? 65535 : qi);
        srow[ncol[j]] = (unsigned short)qi;
      }
    }
}

// ---- select + exact rescore: one wave per source row ------------------------
// sweep 1: ushort8 loads, per-512-candidate chunk-mins kept in registers;
// sweep 2 re-reads only chunks with cmin <= min+64, rescoring hits in fp32
// (hi + lo/4096 reconstruction). Tie-break: lowest n on exact equality.
template <int K, int CH>
__global__ __launch_bounds__(256) void select_rescore(
    const unsigned short* __restrict__ sc,
    const _Float16* __restrict__ hiA, const _Float16* __restrict__ loA,
    const _Float16* __restrict__ hiB, const _Float16* __restrict__ loB,
    const float* __restrict__ hn, unsigned* __restrict__ idx, int M, int N) {
  const int w = threadIdx.x >> 6, lane = threadIdx.x & 63;
  const int row = blockIdx.x * 4 + w;
  const int b = blockIdx.y;
  const unsigned short* q = sc + ((size_t)b * M + row) * N;

  unsigned cm[CH];
#pragma unroll
  for (int ch = 0; ch < CH; ++ch) {
    u16x8 v = *(const u16x8*)(q + ch * 512 + lane * 8);
    unsigned m0 = v[0] < v[1] ? v[0] : v[1];
    unsigned m1 = v[2] < v[3] ? v[2] : v[3];
    unsigned m2 = v[4] < v[5] ? v[4] : v[5];
    unsigned m3 = v[6] < v[7] ? v[6] : v[7];
    m0 = m0 < m1 ? m0 : m1;
    m2 = m2 < m3 ? m2 : m3;
    unsigned m = m0 < m2 ? m0 : m2;
#pragma unroll
    for (int off = 32; off >= 1; off >>= 1) {
      unsigned o = (unsigned)__shfl_xor((int)m, off);
      m = o < m ? o : m;
    }
    cm[ch] = m;
  }
  unsigned mn = 0xFFFFu;
#pragma unroll
  for (int ch = 0; ch < CH; ++ch) mn = cm[ch] < mn ? cm[ch] : mn;
  const unsigned thr = mn + 64;

  constexpr int PER = K / 64;
  const float inv = 2.44140625e-4f;
  float sv[PER];
  const _Float16* hA = hiA + ((size_t)b * M + row) * K;
  const _Float16* lA = loA + ((size_t)b * M + row) * K;
#pragma unroll
  for (int i = 0; i < PER; ++i)
    sv[i] = fmaf((float)lA[i * 64 + lane], inv, (float)hA[i * 64 + lane]);

  float bestv = 3.4e38f;
  int bestn = 0x7FFFFFFF;
  const float* hnB = hn + (size_t)b * N;
#pragma unroll
  for (int ch = 0; ch < CH; ++ch) {
    if (cm[ch] > thr) continue;
    u16x8 v = *(const u16x8*)(q + ch * 512 + lane * 8);
#pragma unroll
    for (int e = 0; e < 8; ++e) {
      u64 mask = __ballot((unsigned)v[e] <= thr);
      while (mask) {
        int bit = __ffsll((long long)mask) - 1;
        mask &= mask - 1;
        int n = ch * 512 + bit * 8 + e;
        const _Float16* hB = hiB + ((size_t)b * N + n) * K;
        const _Float16* lB = loB + ((size_t)b * N + n) * K;
        float part = 0.f;
#pragma unroll
        for (int i = 0; i < PER; ++i)
          part = fmaf(sv[i], fmaf((float)lB[i * 64 + lane], inv, (float)hB[i * 64 + lane]), part);
#pragma unroll
        for (int off = 32; off >= 1; off >>= 1) part += __shfl_xor(part, off);
        float scf = hnB[n] - part;
        if (scf < bestv || (scf == bestv && n < bestn)) { bestv = scf; bestn = n; }
      }
    }
  }
  if (lane == 0) idx[(size_t)b * M + row] = (unsigned)bestn;
}

// ---- write c1 = [src1 | gather(tar1, idx1)] ---------------------------------
__global__ __launch_bounds__(256) void write_c1(const float* __restrict__ src1,
                                                const float* __restrict__ tar1,
                                                const unsigned* __restrict__ idx,
                                                float* __restrict__ out) {
  const int b = blockIdx.y, c = blockIdx.x;  // c in [0,2048)
  float* orow = out + ((size_t)b * 6144 + c) * 4096;
  if (c < 1024) {
    const float4* s4 = (const float4*)(src1 + ((size_t)b * 1024 + c) * 4096);
    float4* o4 = (float4*)orow;
#pragma unroll
    for (int i = 0; i < 4; ++i) o4[threadIdx.x + i * 256] = s4[threadIdx.x + i * 256];
  } else {
    const float* trow = tar1 + ((size_t)b * 1024 + (c - 1024)) * 4096;
    const unsigned* ib = idx + (size_t)b * 4096;
    for (int p = threadIdx.x; p < 4096; p += 256) orow[p] = trow[ib[p]];
  }
}

// ---- bilinear x2 upsample of c2 = [src2 | gather(tar2, idx2)] ---------------
__global__ __launch_bounds__(256) void upsample2(const float* __restrict__ src2,
                                                 const float* __restrict__ tar2,
                                                 const unsigned* __restrict__ idx2,
                                                 float* __restrict__ out) {
  __shared__ float row[1024];
  int b = blockIdx.y, c = blockIdx.x;
  if (c < 2048) {
    const float* in = src2 + ((size_t)b * 2048 + c) * 1024;
    for (int p = threadIdx.x; p < 1024; p += 256) row[p] = in[p];
  } else {
    const float* trow = tar2 + ((size_t)b * 2048 + (c - 2048)) * 1024;
    const unsigned* ib = idx2 + (size_t)b * 1024;
    for (int p = threadIdx.x; p < 1024; p += 256) row[p] = trow[ib[p]];
  }
  __syncthreads();
  float* orow = out + ((size_t)b * 6144 + 2048 + c) * 4096;
  for (int q = threadIdx.x; q < 4096; q += 256) {
    int y = q >> 6, x = q & 63;
    int ky = y >> 1, kx = x >> 1;
    int y0, y1, x0, x1;
    float wy0, wy1, wx0, wx1;
    if (y & 1) { y0 = ky; y1 = (ky + 1 < 32) ? ky + 1 : 31; wy0 = 0.75f; wy1 = 0.25f; }
    else       { y0 = (ky > 0) ? ky - 1 : 0; y1 = ky;       wy0 = 0.25f; wy1 = 0.75f; }
    if (x & 1) { x0 = kx; x1 = (kx + 1 < 32) ? kx + 1 : 31; wx0 = 0.75f; wx1 = 0.25f; }
    else       { x0 = (kx > 0) ? kx - 1 : 0; x1 = kx;       wx0 = 0.25f; wx1 = 0.75f; }
    float v = wy0 * (wx0 * row[y0 * 32 + x0] + wx1 * row[y0 * 32 + x1]) +
              wy1 * (wx0 * row[y1 * 32 + x0] + wx1 * row[y1 * 32 + x1]);
    orow[q] = v;
  }
}

// ---------------- launch -----------------------------------------------------
extern "C" void kernel_launch(void* const* d_in, const int* in_sizes, int n_in,
                              void* d_out, int out_size, void* d_ws, size_t ws_size,
                              hipStream_t stream) {
  const float* src1 = (const float*)d_in[0];  // [4,1024,64,64]
  const float* tar1 = (const float*)d_in[1];
  const float* src2 = (const float*)d_in[2];  // [4,2048,32,32]
  const float* tar2 = (const float*)d_in[3];
  float* out = (float*)d_out;                 // [4,6144,64,64] = 384 MiB

  // scratch in d_out (consumed before the final output writes):
  u8* scratch = (u8*)d_out;
  _Float16* hi1s = (_Float16*)scratch;                       // 32 MiB [4,4096,1024]
  _Float16* lo1s = (_Float16*)(scratch + (32ull << 20));     // 32 MiB
  _Float16* hi1t = (_Float16*)(scratch + (64ull << 20));     // 32 MiB
  _Float16* lo1t = (_Float16*)(scratch + (96ull << 20));     // 32 MiB
  _Float16* hi2s = (_Float16*)(scratch + (128ull << 20));    // 16 MiB [4,1024,2048]
  _Float16* lo2s = (_Float16*)(scratch + (144ull << 20));    // 16 MiB
  _Float16* hi2t = (_Float16*)(scratch + (160ull << 20));    // 16 MiB
  _Float16* lo2t = (_Float16*)(scratch + (176ull << 20));    // 16 MiB
  unsigned short* sc1 = (unsigned short*)(scratch + (192ull << 20));  // 128 MiB
  unsigned short* sc2 = (unsigned short*)(scratch + (320ull << 20));  // 8 MiB
  float* hnp1 = (float*)(scratch + (328ull << 20));          // 2 MiB [4,32,4096]
  float* hnp2 = (float*)(scratch + (331ull << 20));          // 1 MiB [4,64,1024]

  float* hn1 = (float*)d_ws;              // 4*4096 f32
  float* hn2 = hn1 + 4 * 4096;            // 4*1024 f32
  unsigned* idx1 = (unsigned*)(hn2 + 4 * 1024);  // 4*4096 u32
  unsigned* idx2 = idx1 + 4 * 4096;              // 4*1024 u32

  split_convert<false><<<dim3(32, 16, 4), 256, 0, stream>>>(src1, hi1s, lo1s, nullptr, 1024, 4096);
  split_convert<true><<<dim3(32, 16, 4), 256, 0, stream>>>(tar1, hi1t, lo1t, hnp1, 1024, 4096);
  split_convert<false><<<dim3(64, 4, 4), 256, 0, stream>>>(src2, hi2s, lo2s, nullptr, 2048, 1024);
  split_convert<true><<<dim3(64, 4, 4), 256, 0, stream>>>(tar2, hi2t, lo2t, hnp2, 2048, 1024);

  hn_reduce<<<dim3(16, 4), 256, 0, stream>>>(hnp1, hn1, 32, 4096);
  hn_reduce<<<dim3(4, 4), 256, 0, stream>>>(hnp2, hn2, 64, 1024);

  // level 1: 256x256 tile, M=N=4096, K=1024 (NT=16); 16x16 blocks x4 = 1024
  nn_filter8<8, 4, 4, 512><<<1024, 512, 0, stream>>>(
      (const u8*)hi1s, (const u8*)hi1t, hn1, sc1, 4096, 4096, 16, 16, 16);
  // level 2: 128x128 tile, M=N=1024, K=2048 (NT=32); 8x8 blocks x4 = 256
  nn_filter8<4, 4, 2, 256><<<256, 256, 0, stream>>>(
      (const u8*)hi2s, (const u8*)hi2t, hn2, sc2, 1024, 1024, 32, 8, 8);

  select_rescore<1024, 8><<<dim3(1024, 4), 256, 0, stream>>>(
      sc1, hi1s, lo1s, hi1t, lo1t, hn1, idx1, 4096, 4096);
  select_rescore<2048, 2><<<dim3(256, 4), 256, 0, stream>>>(
      sc2, hi2s, lo2s, hi2t, lo2t, hn2, idx2, 1024, 1024);

  write_c1<<<dim3(2048, 4), 256, 0, stream>>>(src1, tar1, idx1, out);
  upsample2<<<dim3(4096, 4), 256, 0, stream>>>(src2, tar2, idx2, out);
}